// Round 10
// baseline (91.902 us; speedup 1.0000x reference)
//
#include <hip/hip_runtime.h>
#include <math.h>

#define BB 8
#define NN 4096
#define PP 16
#define SS 200
#define NCHUNK 4                  // 1024-point chunks per (b,p)
#define NBLK (BB*PP*NCHUNK)       // 512 blocks

// ws layout (floats): cub_part[512] | cd_part[512] | colsum_part[512]
// Every slot unconditionally written by its block -> no pre-zeroing.

// grid = 512 blocks of 256 threads; block = (b,p,chunk); 4 points/thread.
// Chamfer loop: register double-buffered 4-sample groups -> ds_read latency
// hidden behind the previous group's 64 VALU ops.
__global__ __launch_bounds__(256) void main_kernel(
    const float* __restrict__ pc, const float* __restrict__ normals,
    const float* __restrict__ trans, const float* __restrict__ rotate,
    const float* __restrict__ scale, const float* __restrict__ shape_eps,
    const float* __restrict__ assign,
    const float* __restrict__ etas, const float* __restrict__ omegas,
    float* __restrict__ cub_part, float* __restrict__ cd_part,
    float* __restrict__ colsum_part) {
    __shared__ float4 Xs[SS];
    __shared__ float rc[4], rd[4], ra[4];

    int blk = blockIdx.x;
    int chunk = blk & (NCHUNK-1);
    int bp = blk >> 2;             // b*PP + p
    int b = bp >> 4;
    int p = bp & 15;

    // ---- in-block sample table (threads 0..SS-1), fast intrinsics ----
    if (threadIdx.x < SS) {
        int idx = bp * SS + threadIdx.x;
        float eta = etas[idx];
        float om  = omegas[idx];
        if (eta == 0.f) eta = 1e-6f;
        if (om  == 0.f) om  = 1e-6f;
        float a1 = scale[bp*3+0], a2 = scale[bp*3+1], a3 = scale[bp*3+2];
        float e1 = shape_eps[bp*2+0], e2 = shape_eps[bp*2+1];
        float ce, se, co, so;
        __sincosf(eta, &se, &ce);
        __sincosf(om,  &so, &co);
        auto fexp = [](float x, float pw) {
            float sg = (x > 0.f) ? 1.f : ((x < 0.f) ? -1.f : 0.f);
            return sg * __powf(fabsf(x), pw);
        };
        float fce = fexp(ce, e1);
        float x = a1 * fce * fexp(co, e2);
        float y = a2 * fce * fexp(so, e2);
        float z = a3 * fexp(se, e1);
        auto clampv = [](float v) {
            return ((v > 0.f) ? 1.f : -1.f) * fmaxf(fabsf(v), 1e-6f);
        };
        x = clampv(x); y = clampv(y); z = clampv(z);
        Xs[threadIdx.x] = make_float4(-2.f*x, -2.f*y, -2.f*z, x*x + y*y + z*z);
    }

    // wave-uniform primitive params -> scalar regs
    float tx = trans[bp*3+0], ty = trans[bp*3+1], tz = trans[bp*3+2];
    float R0 = rotate[bp*9+0], R1 = rotate[bp*9+1], R2 = rotate[bp*9+2];
    float R3 = rotate[bp*9+3], R4 = rotate[bp*9+4], R5 = rotate[bp*9+5];
    float R6 = rotate[bp*9+6], R7 = rotate[bp*9+7], R8 = rotate[bp*9+8];
    float sx = scale[bp*3+0], sy = scale[bp*3+1], sz = scale[bp*3+2];

    // ---- phase 1a: batch ALL global loads (latency overlaps sample-gen) ----
    float px[4], py[4], pz[4], qx[4], qy[4], qz[4], aw[4];
#pragma unroll
    for (int j = 0; j < 4; j++) {
        int n = chunk * 1024 + j * 256 + threadIdx.x;
        size_t base = ((size_t)b * NN + n) * 3;
        px[j] = pc[base+0]; py[j] = pc[base+1]; pz[j] = pc[base+2];
        qx[j] = normals[base+0]; qy[j] = normals[base+1]; qz[j] = normals[base+2];
        aw[j] = assign[((size_t)b * NN + n) * PP + p];   // used only at the end
    }

    // ---- phase 1b: transform + cuboid (aw NOT touched here) ----
    float y0[4], y1[4], y2[4], ysq[4], cubd[4];
#pragma unroll
    for (int j = 0; j < 4; j++) {
        float d0 = px[j] - tx, d1 = py[j] - ty, d2 = pz[j] - tz;
        y0[j] = R0*d0 + R3*d1 + R6*d2;
        y1[j] = R1*d0 + R4*d1 + R7*d2;
        y2[j] = R2*d0 + R5*d1 + R8*d2;
        float e0 = qx[j] - tx, e1 = qy[j] - ty, e2 = qz[j] - tz;
        float m0 = R0*e0 + R3*e1 + R6*e2;
        float m1 = R1*e0 + R4*e1 + R7*e2;
        float m2 = R2*e0 + R5*e1 + R8*e2;

        float rn = 1.f / fmaxf(sqrtf(m0*m0 + m1*m1 + m2*m2), 1e-4f);
        float s0 = -m0*rn, s1 = m0*rn, s2 = -m1*rn, s3 = m1*rn, s4 = -m2*rn, s5 = m2*rn;
        int fidx = 0; float best = s0;
        if (s1 > best) { best = s1; fidx = 1; }
        if (s2 > best) { best = s2; fidx = 2; }
        if (s3 > best) { best = s3; fidx = 3; }
        if (s4 > best) { best = s4; fidx = 4; }
        if (s5 > best) { best = s5; fidx = 5; }
        int axis = fidx >> 1;
        float sgn = (fidx & 1) ? 1.f : -1.f;
        float pjx = fminf(fmaxf(y0[j], -sx), sx);
        float pjy = fminf(fmaxf(y1[j], -sy), sy);
        float pjz = fminf(fmaxf(y2[j], -sz), sz);
        if (axis == 0)      pjx = sgn * sx;
        else if (axis == 1) pjy = sgn * sy;
        else                pjz = sgn * sz;
        float dxx = pjx - y0[j], dyy = pjy - y1[j], dzz = pjz - y2[j];
        cubd[j] = dxx*dxx + dyy*dyy + dzz*dzz;
        ysq[j] = y0[j]*y0[j] + y1[j]*y1[j] + y2[j]*y2[j];
    }

    __syncthreads();   // Xs ready

    // ---- chamfer: register double-buffered 4-sample groups ----
    float mA0=1e30f, mA1=1e30f, mA2=1e30f, mA3=1e30f;
    float mB0=1e30f, mB1=1e30f, mB2=1e30f, mB3=1e30f;
    float4 A0, A1, A2, A3, B0, B1, B2, B3;

#define DOT(X,J) fmaf((X).x, y0[J], fmaf((X).y, y1[J], fmaf((X).z, y2[J], (X).w)))
#define COMPUTE_A  \
    mA0 = fminf(fminf(fminf(fminf(mA0, DOT(A0,0)), DOT(A1,0)), DOT(A2,0)), DOT(A3,0)); \
    mA1 = fminf(fminf(fminf(fminf(mA1, DOT(A0,1)), DOT(A1,1)), DOT(A2,1)), DOT(A3,1)); \
    mA2 = fminf(fminf(fminf(fminf(mA2, DOT(A0,2)), DOT(A1,2)), DOT(A2,2)), DOT(A3,2)); \
    mA3 = fminf(fminf(fminf(fminf(mA3, DOT(A0,3)), DOT(A1,3)), DOT(A2,3)), DOT(A3,3));
#define COMPUTE_B  \
    mB0 = fminf(fminf(fminf(fminf(mB0, DOT(B0,0)), DOT(B1,0)), DOT(B2,0)), DOT(B3,0)); \
    mB1 = fminf(fminf(fminf(fminf(mB1, DOT(B0,1)), DOT(B1,1)), DOT(B2,1)), DOT(B3,1)); \
    mB2 = fminf(fminf(fminf(fminf(mB2, DOT(B0,2)), DOT(B1,2)), DOT(B2,2)), DOT(B3,2)); \
    mB3 = fminf(fminf(fminf(fminf(mB3, DOT(B0,3)), DOT(B1,3)), DOT(B2,3)), DOT(B3,3));

    A0 = Xs[0]; A1 = Xs[1]; A2 = Xs[2]; A3 = Xs[3];
#pragma unroll 1
    for (int it = 0; it < 24; ++it) {
        int s = it * 8;
        B0 = Xs[s+4]; B1 = Xs[s+5]; B2 = Xs[s+6]; B3 = Xs[s+7];
        COMPUTE_A;
        A0 = Xs[s+8]; A1 = Xs[s+9]; A2 = Xs[s+10]; A3 = Xs[s+11];
        COMPUTE_B;
    }
    // epilogue: A holds samples 192..195
    B0 = Xs[196]; B1 = Xs[197]; B2 = Xs[198]; B3 = Xs[199];
    COMPUTE_A;
    COMPUTE_B;

    float mn0 = fminf(mA0, mB0), mn1 = fminf(mA1, mB1);
    float mn2 = fminf(mA2, mB2), mn3 = fminf(mA3, mB3);

    float acc_cd = fmaxf(mn0 + ysq[0], 0.f) * aw[0]
                 + fmaxf(mn1 + ysq[1], 0.f) * aw[1]
                 + fmaxf(mn2 + ysq[2], 0.f) * aw[2]
                 + fmaxf(mn3 + ysq[3], 0.f) * aw[3];
    float acc_cub = cubd[0]*aw[0] + cubd[1]*aw[1] + cubd[2]*aw[2] + cubd[3]*aw[3];
    float acc_as  = aw[0] + aw[1] + aw[2] + aw[3];

    // block reduction (3 values), one plain store per block (no atomics)
#pragma unroll
    for (int off = 32; off > 0; off >>= 1) {
        acc_cub += __shfl_down(acc_cub, off, 64);
        acc_cd  += __shfl_down(acc_cd,  off, 64);
        acc_as  += __shfl_down(acc_as,  off, 64);
    }
    int wave = threadIdx.x >> 6, lane = threadIdx.x & 63;
    if (lane == 0) { rc[wave] = acc_cub; rd[wave] = acc_cd; ra[wave] = acc_as; }
    __syncthreads();
    if (threadIdx.x == 0) {
        cub_part[blk]    = rc[0]+rc[1]+rc[2]+rc[3];
        cd_part[blk]     = rd[0]+rd[1]+rd[2]+rd[3];
        colsum_part[blk] = ra[0]+ra[1]+ra[2]+ra[3];
    }
}

__global__ void finalize_kernel(const float* __restrict__ exist,
                                const float* __restrict__ cub_part,
                                const float* __restrict__ cd_part,
                                const float* __restrict__ colsum_part,
                                float* __restrict__ out) {
    int t = threadIdx.x;   // 256 threads
    __shared__ float bce_s[128], sq_s[128], rcub[4], rcd[4];

    float c1 = cub_part[t] + cub_part[t + 256];
    float c2 = cd_part[t]  + cd_part[t + 256];
#pragma unroll
    for (int off = 32; off > 0; off >>= 1) {
        c1 += __shfl_down(c1, off, 64);
        c2 += __shfl_down(c2, off, 64);
    }
    int wave = t >> 6, lane = t & 63;
    if (lane == 0) { rcub[wave] = c1; rcd[wave] = c2; }

    if (t < 128) {
        float cs = colsum_part[t*4+0] + colsum_part[t*4+1]
                 + colsum_part[t*4+2] + colsum_part[t*4+3];
        float gt = (cs > 24.0f) ? 1.f : 0.f;
        float pe = exist[t];
        float lg  = fmaxf(__logf(pe), -100.f);
        float lg1 = fmaxf(__logf(1.f - pe), -100.f);
        bce_s[t] = -(gt * lg + (1.f - gt) * lg1);
        sq_s[t] = sqrtf(cs / (float)NN + 0.01f);
    }
    __syncthreads();
    if (t == 0) {
        float ext = 0.f;
        for (int i = 0; i < 128; i++) ext += bce_s[i];
        ext /= 128.f;
        float sps = 0.f;
        for (int bb = 0; bb < 8; bb++) {
            float mb = 0.f;
            for (int pp2 = 0; pp2 < 16; pp2++) mb += sq_s[bb*16 + pp2];
            mb /= 16.f;
            sps += mb * mb;
        }
        sps /= 8.f;
        float cub = (rcub[0]+rcub[1]+rcub[2]+rcub[3]) / (float)(BB * NN);
        float p2p = (rcd[0]+rcd[1]+rcd[2]+rcd[3]) / (float)(BB * NN);
        float cd  = 2.f * p2p;
        out[0] = 1.0f * cub + 1.0f * cd + 0.1f * ext + 0.1f * sps;
    }
}

extern "C" void kernel_launch(void* const* d_in, const int* in_sizes, int n_in,
                              void* d_out, int out_size, void* d_ws, size_t ws_size,
                              hipStream_t stream) {
    const float* pc        = (const float*)d_in[0];
    const float* normals   = (const float*)d_in[1];
    const float* trans     = (const float*)d_in[2];
    const float* rotate    = (const float*)d_in[3];
    const float* scale     = (const float*)d_in[4];
    const float* shape_eps = (const float*)d_in[5];
    const float* exist     = (const float*)d_in[6];
    const float* assign    = (const float*)d_in[7];
    const float* etas      = (const float*)d_in[8];
    const float* omegas    = (const float*)d_in[9];

    float* ws = (float*)d_ws;
    float* cub_part    = ws;
    float* cd_part     = ws + NBLK;
    float* colsum_part = ws + 2*NBLK;

    main_kernel<<<NBLK, 256, 0, stream>>>(
        pc, normals, trans, rotate, scale, shape_eps, assign, etas, omegas,
        cub_part, cd_part, colsum_part);
    finalize_kernel<<<1, 256, 0, stream>>>(
        exist, cub_part, cd_part, colsum_part, (float*)d_out);
}

// Round 11
// 90.818 us; speedup vs baseline: 1.0119x; 1.0119x over previous
//
#include <hip/hip_runtime.h>
#include <math.h>

#define BB 8
#define NN 4096
#define PP 16
#define SS 200
#define NCHUNK 8                  // 512-point chunks per (b,p)
#define NBLK (BB*PP*NCHUNK)       // 1024 blocks -> 4 blocks/CU, 4 waves/SIMD

// ws layout (floats): cub_part[1024] | cd_part[1024] | colsum_part[1024]
// Every slot unconditionally written by its block -> no pre-zeroing.

// grid = 1024 blocks of 256 threads; block = (b,p,chunk); 2 points/thread.
__global__ __launch_bounds__(256) void main_kernel(
    const float* __restrict__ pc, const float* __restrict__ normals,
    const float* __restrict__ trans, const float* __restrict__ rotate,
    const float* __restrict__ scale, const float* __restrict__ shape_eps,
    const float* __restrict__ assign,
    const float* __restrict__ etas, const float* __restrict__ omegas,
    float* __restrict__ cub_part, float* __restrict__ cd_part,
    float* __restrict__ colsum_part) {
    __shared__ float4 Xs[SS];
    __shared__ float rc[4], rd[4], ra[4];

    int blk = blockIdx.x;
    int chunk = blk & (NCHUNK-1);
    int bp = blk >> 3;             // b*PP + p
    int b = bp >> 4;
    int p = bp & 15;

    // ---- in-block sample table (threads 0..SS-1), fast intrinsics ----
    if (threadIdx.x < SS) {
        int idx = bp * SS + threadIdx.x;
        float eta = etas[idx];
        float om  = omegas[idx];
        if (eta == 0.f) eta = 1e-6f;
        if (om  == 0.f) om  = 1e-6f;
        float a1 = scale[bp*3+0], a2 = scale[bp*3+1], a3 = scale[bp*3+2];
        float e1 = shape_eps[bp*2+0], e2 = shape_eps[bp*2+1];
        float ce, se, co, so;
        __sincosf(eta, &se, &ce);
        __sincosf(om,  &so, &co);
        auto fexp = [](float x, float pw) {
            float sg = (x > 0.f) ? 1.f : ((x < 0.f) ? -1.f : 0.f);
            return sg * __powf(fabsf(x), pw);
        };
        float fce = fexp(ce, e1);
        float x = a1 * fce * fexp(co, e2);
        float y = a2 * fce * fexp(so, e2);
        float z = a3 * fexp(se, e1);
        auto clampv = [](float v) {
            return ((v > 0.f) ? 1.f : -1.f) * fmaxf(fabsf(v), 1e-6f);
        };
        x = clampv(x); y = clampv(y); z = clampv(z);
        Xs[threadIdx.x] = make_float4(-2.f*x, -2.f*y, -2.f*z, x*x + y*y + z*z);
    }

    // wave-uniform primitive params -> scalar regs
    float tx = trans[bp*3+0], ty = trans[bp*3+1], tz = trans[bp*3+2];
    float R0 = rotate[bp*9+0], R1 = rotate[bp*9+1], R2 = rotate[bp*9+2];
    float R3 = rotate[bp*9+3], R4 = rotate[bp*9+4], R5 = rotate[bp*9+5];
    float R6 = rotate[bp*9+6], R7 = rotate[bp*9+7], R8 = rotate[bp*9+8];
    float sx = scale[bp*3+0], sy = scale[bp*3+1], sz = scale[bp*3+2];

    float y0[2], y1[2], y2[2], ysq[2], aw[2], cubd[2];
#pragma unroll
    for (int j = 0; j < 2; j++) {
        int n = chunk * 512 + j * 256 + threadIdx.x;
        size_t base = ((size_t)b * NN + n) * 3;
        float px = pc[base+0], py = pc[base+1], pz = pc[base+2];
        float qx = normals[base+0], qy = normals[base+1], qz = normals[base+2];
        aw[j] = assign[((size_t)b * NN + n) * PP + p];

        float d0 = px - tx, d1 = py - ty, d2 = pz - tz;
        y0[j] = R0*d0 + R3*d1 + R6*d2;
        y1[j] = R1*d0 + R4*d1 + R7*d2;
        y2[j] = R2*d0 + R5*d1 + R8*d2;
        float e0 = qx - tx, e1 = qy - ty, e2 = qz - tz;
        float m0 = R0*e0 + R3*e1 + R6*e2;
        float m1 = R1*e0 + R4*e1 + R7*e2;
        float m2 = R2*e0 + R5*e1 + R8*e2;

        // ---- cuboid loss ----
        float rn = 1.f / fmaxf(sqrtf(m0*m0 + m1*m1 + m2*m2), 1e-4f);
        float s0 = -m0*rn, s1 = m0*rn, s2 = -m1*rn, s3 = m1*rn, s4 = -m2*rn, s5 = m2*rn;
        int fidx = 0; float best = s0;
        if (s1 > best) { best = s1; fidx = 1; }
        if (s2 > best) { best = s2; fidx = 2; }
        if (s3 > best) { best = s3; fidx = 3; }
        if (s4 > best) { best = s4; fidx = 4; }
        if (s5 > best) { best = s5; fidx = 5; }
        int axis = fidx >> 1;
        float sgn = (fidx & 1) ? 1.f : -1.f;
        float pjx = fminf(fmaxf(y0[j], -sx), sx);
        float pjy = fminf(fmaxf(y1[j], -sy), sy);
        float pjz = fminf(fmaxf(y2[j], -sz), sz);
        if (axis == 0)      pjx = sgn * sx;
        else if (axis == 1) pjy = sgn * sy;
        else                pjz = sgn * sz;
        float dxx = pjx - y0[j], dyy = pjy - y1[j], dzz = pjz - y2[j];
        cubd[j] = dxx*dxx + dyy*dyy + dzz*dzz;
        ysq[j] = y0[j]*y0[j] + y1[j]*y1[j] + y2[j]*y2[j];
    }

    __syncthreads();   // Xs ready

    // ---- chamfer: 200 samples from LDS; 2 chains x 2 points ----
    float mmA[2] = {1e30f, 1e30f};
    float mmB[2] = {1e30f, 1e30f};
#pragma unroll 8
    for (int s = 0; s < SS; s += 2) {
        float4 xa = Xs[s+0], xb = Xs[s+1];
#pragma unroll
        for (int j = 0; j < 2; j++) {
            mmA[j] = fminf(mmA[j], fmaf(xa.x, y0[j], fmaf(xa.y, y1[j], fmaf(xa.z, y2[j], xa.w))));
            mmB[j] = fminf(mmB[j], fmaf(xb.x, y0[j], fmaf(xb.y, y1[j], fmaf(xb.z, y2[j], xb.w))));
        }
    }
    float acc_cd = 0.f, acc_cub = 0.f, acc_as = 0.f;
#pragma unroll
    for (int j = 0; j < 2; j++) {
        float mn = fminf(mmA[j], mmB[j]);
        acc_cd  += fmaxf(mn + ysq[j], 0.f) * aw[j];
        acc_cub += cubd[j] * aw[j];
        acc_as  += aw[j];
    }

    // block reduction (3 values), one plain store per block (no atomics)
#pragma unroll
    for (int off = 32; off > 0; off >>= 1) {
        acc_cub += __shfl_down(acc_cub, off, 64);
        acc_cd  += __shfl_down(acc_cd,  off, 64);
        acc_as  += __shfl_down(acc_as,  off, 64);
    }
    int wave = threadIdx.x >> 6, lane = threadIdx.x & 63;
    if (lane == 0) { rc[wave] = acc_cub; rd[wave] = acc_cd; ra[wave] = acc_as; }
    __syncthreads();
    if (threadIdx.x == 0) {
        cub_part[blk]    = rc[0]+rc[1]+rc[2]+rc[3];
        cd_part[blk]     = rd[0]+rd[1]+rd[2]+rd[3];
        colsum_part[blk] = ra[0]+ra[1]+ra[2]+ra[3];
    }
}

__global__ void finalize_kernel(const float* __restrict__ exist,
                                const float* __restrict__ cub_part,
                                const float* __restrict__ cd_part,
                                const float* __restrict__ colsum_part,
                                float* __restrict__ out) {
    int t = threadIdx.x;   // 256 threads
    __shared__ float bce_s[128], sq_s[128], rcub[4], rcd[4];

    float c1 = 0.f, c2 = 0.f;
#pragma unroll
    for (int i = 0; i < 4; i++) {
        c1 += cub_part[t + 256*i];
        c2 += cd_part[t + 256*i];
    }
#pragma unroll
    for (int off = 32; off > 0; off >>= 1) {
        c1 += __shfl_down(c1, off, 64);
        c2 += __shfl_down(c2, off, 64);
    }
    int wave = t >> 6, lane = t & 63;
    if (lane == 0) { rcub[wave] = c1; rcd[wave] = c2; }

    if (t < 128) {
        float cs = 0.f;
#pragma unroll
        for (int c = 0; c < NCHUNK; c++) cs += colsum_part[t*NCHUNK + c];
        float gt = (cs > 24.0f) ? 1.f : 0.f;
        float pe = exist[t];
        float lg  = fmaxf(__logf(pe), -100.f);
        float lg1 = fmaxf(__logf(1.f - pe), -100.f);
        bce_s[t] = -(gt * lg + (1.f - gt) * lg1);
        sq_s[t] = sqrtf(cs / (float)NN + 0.01f);
    }
    __syncthreads();
    if (t == 0) {
        float ext = 0.f;
        for (int i = 0; i < 128; i++) ext += bce_s[i];
        ext /= 128.f;
        float sps = 0.f;
        for (int bb = 0; bb < 8; bb++) {
            float mb = 0.f;
            for (int pp2 = 0; pp2 < 16; pp2++) mb += sq_s[bb*16 + pp2];
            mb /= 16.f;
            sps += mb * mb;
        }
        sps /= 8.f;
        float cub = (rcub[0]+rcub[1]+rcub[2]+rcub[3]) / (float)(BB * NN);
        float p2p = (rcd[0]+rcd[1]+rcd[2]+rcd[3]) / (float)(BB * NN);
        float cd  = 2.f * p2p;
        out[0] = 1.0f * cub + 1.0f * cd + 0.1f * ext + 0.1f * sps;
    }
}

extern "C" void kernel_launch(void* const* d_in, const int* in_sizes, int n_in,
                              void* d_out, int out_size, void* d_ws, size_t ws_size,
                              hipStream_t stream) {
    const float* pc        = (const float*)d_in[0];
    const float* normals   = (const float*)d_in[1];
    const float* trans     = (const float*)d_in[2];
    const float* rotate    = (const float*)d_in[3];
    const float* scale     = (const float*)d_in[4];
    const float* shape_eps = (const float*)d_in[5];
    const float* exist     = (const float*)d_in[6];
    const float* assign    = (const float*)d_in[7];
    const float* etas      = (const float*)d_in[8];
    const float* omegas    = (const float*)d_in[9];

    float* ws = (float*)d_ws;
    float* cub_part    = ws;
    float* cd_part     = ws + NBLK;
    float* colsum_part = ws + 2*NBLK;

    main_kernel<<<NBLK, 256, 0, stream>>>(
        pc, normals, trans, rotate, scale, shape_eps, assign, etas, omegas,
        cub_part, cd_part, colsum_part);
    finalize_kernel<<<1, 256, 0, stream>>>(
        exist, cub_part, cd_part, colsum_part, (float*)d_out);
}